// Round 3
// baseline (389.188 us; speedup 1.0000x reference)
//
#include <hip/hip_runtime.h>
#include <hip/hip_bf16.h>

#define BB 4096
#define DIMM 768
#define NHEADS 8
#define DHEAD 96
#define NIDS 751
#define QKSCALE 0.10206207261596577f   // 96^-0.5
#define PVCH 96

typedef _Float16 f16x8 __attribute__((ext_vector_type(8)));
typedef float f32x4 __attribute__((ext_vector_type(4)));

// split-f16: hi = rte(v), lo = residual (unscaled; shares one fp32 accumulator)
__device__ __forceinline__ void split2(float v, _Float16* hi, _Float16* lo) {
    _Float16 h = (_Float16)v;
    *hi = h;
    *lo = (_Float16)(v - (float)h);
}

__device__ __forceinline__ float rec2(const _Float16* hi, const _Float16* lo, size_t idx) {
    return (float)hi[idx] + (float)lo[idx];
}

__device__ __forceinline__ void gl_lds16(const void* g, void* l) {
    __builtin_amdgcn_global_load_lds(
        (const __attribute__((address_space(1))) unsigned int*)g,
        (__attribute__((address_space(3))) unsigned int*)l, 16, 0, 0);
}

__global__ void k_zero(float* p, int n) {
    int i = blockIdx.x * blockDim.x + threadIdx.x;
    if (i < n) p[i] = 0.0f;
}

__global__ void k_split(const float* __restrict__ in, _Float16* __restrict__ hi,
                        _Float16* __restrict__ lo, float s, int n) {
    int i = blockIdx.x * blockDim.x + threadIdx.x;
    if (i < n) split2(in[i] * s, &hi[i], &lo[i]);
}

// W[K][N] -> Th/Tl [N][K] (scaled split), 32x32 tiles via LDS
__global__ void k_tsplit(const float* __restrict__ W, _Float16* __restrict__ Th,
                         _Float16* __restrict__ Tl, float s, int K, int N) {
    __shared__ float tile[32][33];
    int k0 = blockIdx.y * 32, n0 = blockIdx.x * 32;
    int tx = threadIdx.x, ty = threadIdx.y;
    for (int r = ty; r < 32; r += 8) tile[r][tx] = W[(size_t)(k0 + r) * N + n0 + tx];
    __syncthreads();
    for (int r = ty; r < 32; r += 8) {
        int n = n0 + r, k = k0 + tx;
        split2(tile[tx][r] * s, &Th[(size_t)n * K + k], &Tl[(size_t)n * K + k]);
    }
}

// counting sort of labels into groups; single block
__global__ void k_groups(const int* __restrict__ labels, int* __restrict__ perm,
                         int* __restrict__ gstart, int* __restrict__ gcnt) {
    __shared__ int cnt[NIDS], start[NIDS], cur[NIDS];
    int tid = threadIdx.x;
    for (int i = tid; i < NIDS; i += 1024) { cnt[i] = 0; cur[i] = 0; }
    __syncthreads();
    for (int i = tid; i < BB; i += 1024) atomicAdd(&cnt[labels[i]], 1);
    __syncthreads();
    if (tid == 0) { int s = 0; for (int i = 0; i < NIDS; i++) { start[i] = s; s += cnt[i]; } }
    __syncthreads();
    for (int i = tid; i < BB; i += 1024) {
        int lb = labels[i];
        int p = start[lb] + atomicAdd(&cur[lb], 1);
        perm[p] = i;
    }
    for (int i = tid; i < NIDS; i += 1024) { gstart[i] = start[i]; gcnt[i] = cnt[i]; }
}

// C = A(M,K) * B(N,K)^T via split-f16 MFMA, 128x128 tile, BK=32, 4 waves.
// m97 structure + XCD-chunked swizzle (m-panel grouping).
// EPI 0: qkv write (n<1536 -> QK split store scaled x16; else v fp32)
// EPI 1: plain fp32 C store
template <int EPI>
__global__ __launch_bounds__(256) void k_gemm(
    const _Float16* __restrict__ Ah, const _Float16* __restrict__ Al, int lda,
    const _Float16* __restrict__ Bh, const _Float16* __restrict__ Bl, int ldb,
    int K, float inv,
    float* __restrict__ outF, _Float16* __restrict__ oh, _Float16* __restrict__ ol) {
    __shared__ __align__(16) _Float16 sAh[128 * 32];
    __shared__ __align__(16) _Float16 sAl[128 * 32];
    __shared__ __align__(16) _Float16 sBh[128 * 32];
    __shared__ __align__(16) _Float16 sBl[128 * 32];
    const int tid = threadIdx.x;
    const int lane = tid & 63;
    const int wave = tid >> 6;
    const int wm = wave >> 1, wn = wave & 1;
    // bijective XCD-chunked swizzle: consecutive swz share the m-panel (by)
    unsigned wg = blockIdx.y * gridDim.x + blockIdx.x;
    unsigned nwg = gridDim.x * gridDim.y;
    unsigned swz = ((nwg & 7u) == 0u) ? (wg & 7u) * (nwg >> 3) + (wg >> 3) : wg;
    unsigned by = swz / gridDim.x;
    unsigned bx = swz - by * gridDim.x;
    const int m0 = by * 128, n0 = bx * 128;
    const int srow = tid >> 2;
    const int scol = (tid & 3) * 8;
    const int rl = lane & 15;
    const int g8 = (lane >> 4) * 8;

    const _Float16* gAh0 = Ah + (size_t)(m0 + srow) * lda + scol;
    const _Float16* gAh1 = gAh0 + (size_t)64 * lda;
    const _Float16* gAl0 = Al + (size_t)(m0 + srow) * lda + scol;
    const _Float16* gAl1 = gAl0 + (size_t)64 * lda;
    const _Float16* gBh0 = Bh + (size_t)(n0 + srow) * ldb + scol;
    const _Float16* gBh1 = gBh0 + (size_t)64 * ldb;
    const _Float16* gBl0 = Bl + (size_t)(n0 + srow) * ldb + scol;
    const _Float16* gBl1 = gBl0 + (size_t)64 * ldb;
    const int d0 = tid * 8, d1 = 2048 + tid * 8;

    f32x4 acc[4][4];
    const f32x4 vzero = {0.f, 0.f, 0.f, 0.f};
#pragma unroll
    for (int a = 0; a < 4; a++)
#pragma unroll
        for (int b = 0; b < 4; b++) acc[a][b] = vzero;

    for (int kk = 0; kk < K; kk += 32) {
        __syncthreads();
        gl_lds16(gAh0 + kk, sAh + d0);
        gl_lds16(gAh1 + kk, sAh + d1);
        gl_lds16(gAl0 + kk, sAl + d0);
        gl_lds16(gAl1 + kk, sAl + d1);
        gl_lds16(gBh0 + kk, sBh + d0);
        gl_lds16(gBh1 + kk, sBh + d1);
        gl_lds16(gBl0 + kk, sBl + d0);
        gl_lds16(gBl1 + kk, sBl + d1);
        __syncthreads();

        f16x8 ah[4], al[4], bh[4], bl[4];
#pragma unroll
        for (int t = 0; t < 4; t++) {
            ah[t] = *(const f16x8*)&sAh[(wm * 64 + t * 16 + rl) * 32 + g8];
            al[t] = *(const f16x8*)&sAl[(wm * 64 + t * 16 + rl) * 32 + g8];
            bh[t] = *(const f16x8*)&sBh[(wn * 64 + t * 16 + rl) * 32 + g8];
            bl[t] = *(const f16x8*)&sBl[(wn * 64 + t * 16 + rl) * 32 + g8];
        }
#pragma unroll
        for (int a = 0; a < 4; a++)
#pragma unroll
            for (int b = 0; b < 4; b++) {
                acc[a][b] = __builtin_amdgcn_mfma_f32_16x16x32_f16(ah[a], bh[b], acc[a][b], 0, 0, 0);
                acc[a][b] = __builtin_amdgcn_mfma_f32_16x16x32_f16(ah[a], bl[b], acc[a][b], 0, 0, 0);
                acc[a][b] = __builtin_amdgcn_mfma_f32_16x16x32_f16(al[a], bh[b], acc[a][b], 0, 0, 0);
            }
    }

#pragma unroll
    for (int a = 0; a < 4; a++)
#pragma unroll
        for (int b = 0; b < 4; b++) {
            f32x4 d = acc[a][b] * inv;
            int n = n0 + wn * 64 + b * 16 + rl;
            int mb = m0 + wm * 64 + a * 16 + (lane >> 4) * 4;
#pragma unroll
            for (int r = 0; r < 4; r++) {
                int m = mb + r;
                if constexpr (EPI == 0) {
                    if (n < 1536) {
                        split2(d[r] * 16.0f, &oh[(size_t)m * 1536 + n], &ol[(size_t)m * 1536 + n]);
                    } else {
                        outF[(size_t)m * DIMM + (n - 1536)] = d[r];
                    }
                } else {
                    outF[(size_t)m * DIMM + n] = d[r];
                }
            }
        }
}

// Row-sums of exp(q.k*scale): persistent-A structure.
// Grid (32 m-panels, 16 = head*2+nhalf), 256 threads. Q-fragments for the
// whole K=96 live in registers; B (K-rows) staged K-complete into padded LDS;
// per-lane exp-sums accumulate in registers across the 16-tile N-sweep; ONE
// transpose-reduce + 128 atomics per block at the end.
__global__ __launch_bounds__(256, 2) void k_qksum(
    const _Float16* __restrict__ QKh, const _Float16* __restrict__ QKl,
    float* __restrict__ lsum) {
    __shared__ __align__(16) _Float16 sBh[128 * 104];
    __shared__ __align__(16) _Float16 sBl[128 * 104];
    __shared__ float red[128][33];
    const int tid = threadIdx.x;
    const int lane = tid & 63;
    const int wave = tid >> 6;
    const int wm = wave >> 1, wn = wave & 1;
    // swizzle: XCD i owns head i (both n-halves) -> B K-slice (3.1 MB) L2-resident
    unsigned wg = blockIdx.y * 32 + blockIdx.x;
    unsigned swz = (wg & 7u) * 64u + (wg >> 3);
    const int head = (int)(swz >> 6);          // swz/64: 8 heads
    const int nh = (int)((swz >> 5) & 1u);     // n-half
    const int m0 = (int)(swz & 31u) * 128;
    const int cA = head * DHEAD;
    const int cB = DIMM + head * DHEAD;
    const int rl = lane & 15;
    const int g8 = (lane >> 4) * 8;

    // persistent A fragments: same symmetric lane pattern as the LDS path
    f16x8 ah[3][4], al[3][4];
#pragma unroll
    for (int k = 0; k < 3; k++)
#pragma unroll
        for (int a = 0; a < 4; a++) {
            size_t off = (size_t)(m0 + wm * 64 + a * 16 + rl) * 1536 + cA + k * 32 + g8;
            ah[k][a] = *(const f16x8*)(QKh + off);
            al[k][a] = *(const f16x8*)(QKl + off);
        }

    const f32x4 vzero = {0.f, 0.f, 0.f, 0.f};
    f32x4 es[4];
#pragma unroll
    for (int a = 0; a < 4; a++) es[a] = vzero;
    const float esc = QKSCALE * (1.0f / 256.0f);

    for (int nt = 0; nt < 16; nt++) {
        const int n0 = nh * 2048 + nt * 128;
        __syncthreads();   // previous tile's LDS reads complete
        // stage B tile [128 rows][96 cols] hi+lo into [128][104] (pad never read)
#pragma unroll
        for (int rd = 0; rd < 7; rd++) {
            int idx = rd * 256 + tid;
            if (idx < 1664) {
                int row = idx / 13;
                int col = (idx - row * 13) * 8;
                if (col >= 96) col = 0;   // pad granule: load safe garbage
                const size_t so = (size_t)(n0 + row) * 1536 + cB + col;
                gl_lds16(QKh + so, sBh + (size_t)idx * 8);
                gl_lds16(QKl + so, sBl + (size_t)idx * 8);
            }
        }
        __syncthreads();   // vmcnt drained

        f32x4 acc[4][4];
#pragma unroll
        for (int a = 0; a < 4; a++)
#pragma unroll
            for (int b = 0; b < 4; b++) acc[a][b] = vzero;
#pragma unroll
        for (int k = 0; k < 3; k++) {
            f16x8 bh[4], bl[4];
#pragma unroll
            for (int b = 0; b < 4; b++) {
                int r = (wn * 64 + b * 16 + rl) * 104 + k * 32 + g8;
                bh[b] = *(const f16x8*)&sBh[r];
                bl[b] = *(const f16x8*)&sBl[r];
            }
#pragma unroll
            for (int a = 0; a < 4; a++)
#pragma unroll
                for (int b = 0; b < 4; b++) {
                    acc[a][b] = __builtin_amdgcn_mfma_f32_16x16x32_f16(ah[k][a], bh[b], acc[a][b], 0, 0, 0);
                    acc[a][b] = __builtin_amdgcn_mfma_f32_16x16x32_f16(ah[k][a], bl[b], acc[a][b], 0, 0, 0);
                    acc[a][b] = __builtin_amdgcn_mfma_f32_16x16x32_f16(al[k][a], bh[b], acc[a][b], 0, 0, 0);
                }
        }
        // rows owned by this lane are N-invariant: accumulate exp-sums in regs
#pragma unroll
        for (int a = 0; a < 4; a++)
#pragma unroll
            for (int b = 0; b < 4; b++)
#pragma unroll
                for (int r = 0; r < 4; r++)
                    es[a][r] += __expf(acc[a][b][r] * esc);
    }

    // once-per-block transpose-reduce: 32 col-lanes per row -> 1 atomic/row
#pragma unroll
    for (int a = 0; a < 4; a++) {
        int rb = wm * 64 + a * 16 + (lane >> 4) * 4;
#pragma unroll
        for (int r = 0; r < 4; r++) red[rb + r][wn * 16 + rl] = es[a][r];
    }
    __syncthreads();
    if (tid < 128) {
        float s = 0.f;
#pragma unroll
        for (int c = 0; c < 32; c++) s += red[tid][c];
        atomicAdd(&lsum[(size_t)head * BB + m0 + tid], s);
    }
}

// masked PV: block per row i; waves 0..7 compute attn weights for their head over
// the row's label-group; all 768 threads accumulate O[i][h*96+d].
__global__ __launch_bounds__(768) void k_pv(
    const _Float16* __restrict__ QKh, const _Float16* __restrict__ QKl,
    const float* __restrict__ vbuf, const float* __restrict__ lsum,
    const int* __restrict__ labels, const int* __restrict__ perm,
    const int* __restrict__ gstart, const int* __restrict__ gcnt,
    _Float16* __restrict__ oh, _Float16* __restrict__ ol) {
    const int i = blockIdx.x;
    const int tid = threadIdx.x;
    const int wave = tid >> 6;
    const int lane = tid & 63;
    __shared__ float wv[NHEADS][PVCH];
    __shared__ int pidx[PVCH];
    const int lab = labels[i];
    const int st = gstart[lab];
    const int cnt = gcnt[lab];

    float q0 = 0.f, q1 = 0.f, invl = 0.f;
    if (wave < NHEADS) {
        size_t base = (size_t)i * 1536 + wave * DHEAD;
        q0 = rec2(QKh, QKl, base + lane);
        if (lane < 32) q1 = rec2(QKh, QKl, base + 64 + lane);
        invl = 1.0f / lsum[(size_t)wave * BB + i];
    }
    const int h = tid / DHEAD;
    float acc = 0.f;
    for (int b0 = 0; b0 < cnt; b0 += PVCH) {
        int ch = cnt - b0; if (ch > PVCH) ch = PVCH;
        __syncthreads();
        if (tid < ch) pidx[tid] = perm[st + b0 + tid];
        __syncthreads();
        if (wave < NHEADS) {
            for (int jj = 0; jj < ch; jj++) {
                size_t kb = (size_t)pidx[jj] * 1536 + DIMM + wave * DHEAD;
                float p = q0 * rec2(QKh, QKl, kb + lane);
                if (lane < 32) p += q1 * rec2(QKh, QKl, kb + 64 + lane);
#pragma unroll
                for (int m = 32; m >= 1; m >>= 1) p += __shfl_xor(p, m);
                if (lane == 0)
                    wv[wave][jj] = __expf(p * (1.0f / 256.0f) * QKSCALE) * invl;
            }
        }
        __syncthreads();
        for (int jj = 0; jj < ch; jj++)
            acc += wv[h][jj] * vbuf[(size_t)pidx[jj] * DIMM + tid];
    }
    split2(acc * 16.0f, &oh[(size_t)i * DIMM + tid], &ol[(size_t)i * DIMM + tid]);
}

extern "C" void kernel_launch(void* const* d_in, const int* in_sizes, int n_in,
                              void* d_out, int out_size, void* d_ws, size_t ws_size,
                              hipStream_t stream) {
    const float* x = (const float*)d_in[0];
    const int* labels = (const int*)d_in[1];
    const float* Wqkv = (const float*)d_in[2];
    const float* Wout = (const float*)d_in[3];
    float* out = (float*)d_out;

    char* ws = (char*)d_ws;
    size_t off = 0;
    auto alloc = [&](size_t bytes) -> void* {
        void* p = ws + off;
        off += (bytes + 255) & ~(size_t)255;
        return p;
    };
    _Float16* Xh   = (_Float16*)alloc((size_t)BB * DIMM * 2);
    _Float16* Xl   = (_Float16*)alloc((size_t)BB * DIMM * 2);
    _Float16* WqTh = (_Float16*)alloc((size_t)2304 * DIMM * 2);
    _Float16* WqTl = (_Float16*)alloc((size_t)2304 * DIMM * 2);
    _Float16* WoTh = (_Float16*)alloc((size_t)DIMM * DIMM * 2);
    _Float16* WoTl = (_Float16*)alloc((size_t)DIMM * DIMM * 2);
    _Float16* QKh  = (_Float16*)alloc((size_t)BB * 1536 * 2);
    _Float16* QKl  = (_Float16*)alloc((size_t)BB * 1536 * 2);
    float* vbuf    = (float*)alloc((size_t)BB * DIMM * 4);
    float* lsum    = (float*)alloc((size_t)NHEADS * BB * 4);
    _Float16* Oh   = (_Float16*)alloc((size_t)BB * DIMM * 2);
    _Float16* Ol   = (_Float16*)alloc((size_t)BB * DIMM * 2);
    int* perm      = (int*)alloc(BB * 4);
    int* gstart    = (int*)alloc(1024 * 4);
    int* gcnt      = (int*)alloc(1024 * 4);

    k_zero<<<dim3((NHEADS * BB + 255) / 256), dim3(256), 0, stream>>>(lsum, NHEADS * BB);
    k_split<<<dim3((BB * DIMM + 255) / 256), dim3(256), 0, stream>>>(x, Xh, Xl, 16.0f, BB * DIMM);
    k_tsplit<<<dim3(2304 / 32, DIMM / 32), dim3(32, 8), 0, stream>>>(Wqkv, WqTh, WqTl, 256.0f, DIMM, 2304);
    k_tsplit<<<dim3(DIMM / 32, DIMM / 32), dim3(32, 8), 0, stream>>>(Wout, WoTh, WoTl, 256.0f, DIMM, DIMM);
    k_groups<<<dim3(1), dim3(1024), 0, stream>>>(labels, perm, gstart, gcnt);

    // qkv = x @ Wqkv : A scale 16, B scale 256 -> inv 1/4096
    k_gemm<0><<<dim3(2304 / 128, BB / 128, 1), dim3(256), 0, stream>>>(
        Xh, Xl, DIMM, WqTh, WqTl, DIMM, DIMM, 1.0f / 4096.0f, vbuf, QKh, QKl);
    // row sums of exp(q.k * scale)
    k_qksum<<<dim3(32, 16), dim3(256), 0, stream>>>(QKh, QKl, lsum);
    // masked PV
    k_pv<<<dim3(BB), dim3(768), 0, stream>>>(QKh, QKl, vbuf, lsum, labels, perm, gstart, gcnt, Oh, Ol);
    // out = O @ Wout : inv 1/4096
    k_gemm<1><<<dim3(DIMM / 128, BB / 128, 1), dim3(256), 0, stream>>>(
        Oh, Ol, DIMM, WoTh, WoTl, DIMM, DIMM, 1.0f / 4096.0f, out, nullptr, nullptr);
}

// Round 4
// 303.838 us; speedup vs baseline: 1.2809x; 1.2809x over previous
//
#include <hip/hip_runtime.h>
#include <hip/hip_bf16.h>

#define BB 4096
#define DIMM 768
#define NHEADS 8
#define DHEAD 96
#define NIDS 751
#define QKSCALE 0.10206207261596577f   // 96^-0.5
#define PVCH 96

typedef _Float16 f16x8 __attribute__((ext_vector_type(8)));
typedef float f32x4 __attribute__((ext_vector_type(4)));

// split-f16: hi = rte(v), lo = residual (unscaled; shares one fp32 accumulator)
__device__ __forceinline__ void split2(float v, _Float16* hi, _Float16* lo) {
    _Float16 h = (_Float16)v;
    *hi = h;
    *lo = (_Float16)(v - (float)h);
}

__device__ __forceinline__ float rec2(const _Float16* hi, const _Float16* lo, size_t idx) {
    return (float)hi[idx] + (float)lo[idx];
}

__device__ __forceinline__ void gl_lds16(const void* g, void* l) {
    __builtin_amdgcn_global_load_lds(
        (const __attribute__((address_space(1))) unsigned int*)g,
        (__attribute__((address_space(3))) unsigned int*)l, 16, 0, 0);
}

__global__ void k_zero(float* p, int n) {
    int i = blockIdx.x * blockDim.x + threadIdx.x;
    if (i < n) p[i] = 0.0f;
}

__global__ void k_split(const float* __restrict__ in, _Float16* __restrict__ hi,
                        _Float16* __restrict__ lo, float s, int n) {
    int i = blockIdx.x * blockDim.x + threadIdx.x;
    if (i < n) split2(in[i] * s, &hi[i], &lo[i]);
}

// W[K][N] -> Th/Tl [N][K] (scaled split), 32x32 tiles via LDS
__global__ void k_tsplit(const float* __restrict__ W, _Float16* __restrict__ Th,
                         _Float16* __restrict__ Tl, float s, int K, int N) {
    __shared__ float tile[32][33];
    int k0 = blockIdx.y * 32, n0 = blockIdx.x * 32;
    int tx = threadIdx.x, ty = threadIdx.y;
    for (int r = ty; r < 32; r += 8) tile[r][tx] = W[(size_t)(k0 + r) * N + n0 + tx];
    __syncthreads();
    for (int r = ty; r < 32; r += 8) {
        int n = n0 + r, k = k0 + tx;
        split2(tile[tx][r] * s, &Th[(size_t)n * K + k], &Tl[(size_t)n * K + k]);
    }
}

// counting sort of labels into groups; single block, parallel Hillis-Steele scan
__global__ __launch_bounds__(1024) void k_groups(
    const int* __restrict__ labels, int* __restrict__ perm,
    int* __restrict__ gstart, int* __restrict__ gcnt) {
    __shared__ int cnt[1024], scn[1024], strt[1024], cur[1024];
    int tid = threadIdx.x;
    cnt[tid] = 0; cur[tid] = 0;
    __syncthreads();
    for (int i = tid; i < BB; i += 1024) atomicAdd(&cnt[labels[i]], 1);
    __syncthreads();
    int v = cnt[tid];
    scn[tid] = v;
    __syncthreads();
#pragma unroll
    for (int off = 1; off < 1024; off <<= 1) {
        int t = (tid >= off) ? scn[tid - off] : 0;
        __syncthreads();
        scn[tid] += t;
        __syncthreads();
    }
    int st = scn[tid] - v;   // exclusive prefix
    strt[tid] = st;
    if (tid < NIDS) { gstart[tid] = st; gcnt[tid] = v; }
    __syncthreads();
    for (int i = tid; i < BB; i += 1024) {
        int lb = labels[i];
        int p = strt[lb] + atomicAdd(&cur[lb], 1);
        perm[p] = i;
    }
}

// C = A(M,K) * B(N,K)^T via split-f16 MFMA, 128x128 tile, BK=32, 4 waves.
// 2-phase prefetch (T3-minimum): stage tile k+1 into other LDS buffer BEFORE
// computing tile k; ONE barrier per K-step hides stage latency under MFMA.
// EPI 0: qkv write (n<1536 -> QK split store scaled x16; else v fp32)
// EPI 1: plain fp32 C store
template <int EPI>
__global__ __launch_bounds__(256) void k_gemm(
    const _Float16* __restrict__ Ah, const _Float16* __restrict__ Al, int lda,
    const _Float16* __restrict__ Bh, const _Float16* __restrict__ Bl, int ldb,
    int K, float inv,
    float* __restrict__ outF, _Float16* __restrict__ oh, _Float16* __restrict__ ol) {
    __shared__ __align__(16) _Float16 sAh[2][128 * 32];
    __shared__ __align__(16) _Float16 sAl[2][128 * 32];
    __shared__ __align__(16) _Float16 sBh[2][128 * 32];
    __shared__ __align__(16) _Float16 sBl[2][128 * 32];
    const int tid = threadIdx.x;
    const int lane = tid & 63;
    const int wave = tid >> 6;
    const int wm = wave >> 1, wn = wave & 1;
    // bijective XCD-chunked swizzle: consecutive swz share the m-panel (by)
    unsigned wg = blockIdx.y * gridDim.x + blockIdx.x;
    unsigned nwg = gridDim.x * gridDim.y;
    unsigned swz = ((nwg & 7u) == 0u) ? (wg & 7u) * (nwg >> 3) + (wg >> 3) : wg;
    unsigned by = swz / gridDim.x;
    unsigned bx = swz - by * gridDim.x;
    const int m0 = by * 128, n0 = bx * 128;
    const int srow = tid >> 2;
    const int scol = (tid & 3) * 8;
    const int rl = lane & 15;
    const int g8 = (lane >> 4) * 8;

    const _Float16* gAh0 = Ah + (size_t)(m0 + srow) * lda + scol;
    const _Float16* gAh1 = gAh0 + (size_t)64 * lda;
    const _Float16* gAl0 = Al + (size_t)(m0 + srow) * lda + scol;
    const _Float16* gAl1 = gAl0 + (size_t)64 * lda;
    const _Float16* gBh0 = Bh + (size_t)(n0 + srow) * ldb + scol;
    const _Float16* gBh1 = gBh0 + (size_t)64 * ldb;
    const _Float16* gBl0 = Bl + (size_t)(n0 + srow) * ldb + scol;
    const _Float16* gBl1 = gBl0 + (size_t)64 * ldb;
    const int d0 = tid * 8, d1 = 2048 + tid * 8;

    auto stage = [&](int b, int kk) {
        gl_lds16(gAh0 + kk, &sAh[b][d0]);
        gl_lds16(gAh1 + kk, &sAh[b][d1]);
        gl_lds16(gAl0 + kk, &sAl[b][d0]);
        gl_lds16(gAl1 + kk, &sAl[b][d1]);
        gl_lds16(gBh0 + kk, &sBh[b][d0]);
        gl_lds16(gBh1 + kk, &sBh[b][d1]);
        gl_lds16(gBl0 + kk, &sBl[b][d0]);
        gl_lds16(gBl1 + kk, &sBl[b][d1]);
    };

    f32x4 acc[4][4];
    const f32x4 vzero = {0.f, 0.f, 0.f, 0.f};
#pragma unroll
    for (int a = 0; a < 4; a++)
#pragma unroll
        for (int b = 0; b < 4; b++) acc[a][b] = vzero;

    const int KS = K >> 5;
    stage(0, 0);
    for (int ks = 0; ks < KS; ks++) {
        __syncthreads();   // drains own vmcnt(0): buf[ks&1] ready; lgkm: prev reads done
        if (ks + 1 < KS) stage((ks + 1) & 1, (ks + 1) << 5);
        const int cb = ks & 1;
        f16x8 ah[4], al[4], bh[4], bl[4];
#pragma unroll
        for (int t = 0; t < 4; t++) {
            ah[t] = *(const f16x8*)&sAh[cb][(wm * 64 + t * 16 + rl) * 32 + g8];
            al[t] = *(const f16x8*)&sAl[cb][(wm * 64 + t * 16 + rl) * 32 + g8];
            bh[t] = *(const f16x8*)&sBh[cb][(wn * 64 + t * 16 + rl) * 32 + g8];
            bl[t] = *(const f16x8*)&sBl[cb][(wn * 64 + t * 16 + rl) * 32 + g8];
        }
#pragma unroll
        for (int a = 0; a < 4; a++)
#pragma unroll
            for (int b = 0; b < 4; b++) {
                acc[a][b] = __builtin_amdgcn_mfma_f32_16x16x32_f16(ah[a], bh[b], acc[a][b], 0, 0, 0);
                acc[a][b] = __builtin_amdgcn_mfma_f32_16x16x32_f16(ah[a], bl[b], acc[a][b], 0, 0, 0);
                acc[a][b] = __builtin_amdgcn_mfma_f32_16x16x32_f16(al[a], bh[b], acc[a][b], 0, 0, 0);
            }
    }

#pragma unroll
    for (int a = 0; a < 4; a++)
#pragma unroll
        for (int b = 0; b < 4; b++) {
            f32x4 d = acc[a][b] * inv;
            int n = n0 + wn * 64 + b * 16 + rl;
            int mb = m0 + wm * 64 + a * 16 + (lane >> 4) * 4;
#pragma unroll
            for (int r = 0; r < 4; r++) {
                int m = mb + r;
                if constexpr (EPI == 0) {
                    if (n < 1536) {
                        split2(d[r] * 16.0f, &oh[(size_t)m * 1536 + n], &ol[(size_t)m * 1536 + n]);
                    } else {
                        outF[(size_t)m * DIMM + (n - 1536)] = d[r];
                    }
                } else {
                    outF[(size_t)m * DIMM + n] = d[r];
                }
            }
        }
}

// Row-sums of exp(q.k*scale), HI-ONLY (denominator averages 4096 independent
// per-term errors -> relative error ~1e-6; numerator path in k_pv stays split).
// Persistent-A + double-buffered B staging (2-phase prefetch), red aliased on sB.
// Grid 1024: wg&7 = head (XCD-affine), each block sweeps 8 N-tiles of 128.
__global__ __launch_bounds__(256) void k_qksum(
    const _Float16* __restrict__ QKh, float* __restrict__ lsum) {
    __shared__ __align__(16) _Float16 sB[2][128 * 104];
    const int tid = threadIdx.x;
    const int lane = tid & 63;
    const int wave = tid >> 6;
    const int wm = wave >> 1, wn = wave & 1;
    unsigned wg = blockIdx.y * gridDim.x + blockIdx.x;   // 0..1023
    const int head = (int)(wg & 7u);                     // XCD-affine
    unsigned rest = wg >> 3;                             // 0..127
    const int m0 = (int)(rest & 31u) * 128;
    const int nq = (int)(rest >> 5);                     // 0..3 quarter of N
    const int cA = head * DHEAD;
    const int cB = DIMM + head * DHEAD;
    const int rl = lane & 15;
    const int g8 = (lane >> 4) * 8;

    // persistent A fragments (hi only): 12 x f16x8 = 48 VGPR
    f16x8 ah[3][4];
#pragma unroll
    for (int k = 0; k < 3; k++)
#pragma unroll
        for (int a = 0; a < 4; a++)
            ah[k][a] = *(const f16x8*)(QKh +
                (size_t)(m0 + wm * 64 + a * 16 + rl) * 1536 + cA + k * 32 + g8);

    auto stage = [&](int b, int tile) {
        const int n0 = tile * 128;
#pragma unroll
        for (int rd = 0; rd < 7; rd++) {
            int idx = rd * 256 + tid;
            if (idx < 1664) {                 // 128 rows x 13 granules
                int row = idx / 13;
                int c = idx - row * 13;
                int col = (c < 12) ? c * 8 : 0;   // pad granule: safe garbage
                gl_lds16(QKh + (size_t)(n0 + row) * 1536 + cB + col,
                         &sB[b][idx * 8]);    // dest linear = base + lane*16B
            }
        }
    };

    const f32x4 vzero = {0.f, 0.f, 0.f, 0.f};
    f32x4 es[4];
#pragma unroll
    for (int a = 0; a < 4; a++) es[a] = vzero;
    const float esc = QKSCALE * (1.0f / 256.0f);

    stage(0, nq * 8);
    for (int nt = 0; nt < 8; nt++) {
        __syncthreads();   // buf[nt&1] ready; prev reads drained
        if (nt < 7) stage((nt + 1) & 1, nq * 8 + nt + 1);
        const int cb = nt & 1;
        f32x4 acc[4][4];
#pragma unroll
        for (int a = 0; a < 4; a++)
#pragma unroll
            for (int b = 0; b < 4; b++) acc[a][b] = vzero;
#pragma unroll
        for (int k = 0; k < 3; k++) {
            f16x8 bh[4];
#pragma unroll
            for (int b = 0; b < 4; b++)
                bh[b] = *(const f16x8*)&sB[cb][(wn * 64 + b * 16 + rl) * 104 + k * 32 + g8];
#pragma unroll
            for (int a = 0; a < 4; a++)
#pragma unroll
                for (int b = 0; b < 4; b++)
                    acc[a][b] = __builtin_amdgcn_mfma_f32_16x16x32_f16(ah[k][a], bh[b], acc[a][b], 0, 0, 0);
        }
#pragma unroll
        for (int a = 0; a < 4; a++)
#pragma unroll
            for (int b = 0; b < 4; b++)
#pragma unroll
                for (int r = 0; r < 4; r++)
                    es[a][r] += __expf(acc[a][b][r] * esc);
    }

    // once-per-block transpose-reduce; red aliased onto sB[0] (16.9KB < 26.6KB,
    // disjoint from sB[1] which tile-7 compute reads)
    float (*red)[33] = (float (*)[33])&sB[0][0];
#pragma unroll
    for (int a = 0; a < 4; a++) {
        int rb = wm * 64 + a * 16 + (lane >> 4) * 4;
#pragma unroll
        for (int r = 0; r < 4; r++) red[rb + r][wn * 16 + rl] = es[a][r];
    }
    __syncthreads();
    if (tid < 128) {
        float s = 0.f;
#pragma unroll
        for (int c = 0; c < 32; c++) s += red[tid][c];
        atomicAdd(&lsum[(size_t)head * BB + m0 + tid], s);
    }
}

// masked PV: block per row i; waves 0..7 compute attn weights for their head over
// the row's label-group; all 768 threads accumulate O[i][h*96+d].
__global__ __launch_bounds__(768) void k_pv(
    const _Float16* __restrict__ QKh, const _Float16* __restrict__ QKl,
    const float* __restrict__ vbuf, const float* __restrict__ lsum,
    const int* __restrict__ labels, const int* __restrict__ perm,
    const int* __restrict__ gstart, const int* __restrict__ gcnt,
    _Float16* __restrict__ oh, _Float16* __restrict__ ol) {
    const int i = blockIdx.x;
    const int tid = threadIdx.x;
    const int wave = tid >> 6;
    const int lane = tid & 63;
    __shared__ float wv[NHEADS][PVCH];
    __shared__ int pidx[PVCH];
    const int lab = labels[i];
    const int st = gstart[lab];
    const int cnt = gcnt[lab];

    float q0 = 0.f, q1 = 0.f, invl = 0.f;
    if (wave < NHEADS) {
        size_t base = (size_t)i * 1536 + wave * DHEAD;
        q0 = rec2(QKh, QKl, base + lane);
        if (lane < 32) q1 = rec2(QKh, QKl, base + 64 + lane);
        invl = 1.0f / lsum[(size_t)wave * BB + i];
    }
    const int h = tid / DHEAD;
    float acc = 0.f;
    for (int b0 = 0; b0 < cnt; b0 += PVCH) {
        int ch = cnt - b0; if (ch > PVCH) ch = PVCH;
        __syncthreads();
        if (tid < ch) pidx[tid] = perm[st + b0 + tid];
        __syncthreads();
        if (wave < NHEADS) {
            for (int jj = 0; jj < ch; jj++) {
                size_t kb = (size_t)pidx[jj] * 1536 + DIMM + wave * DHEAD;
                float p = q0 * rec2(QKh, QKl, kb + lane);
                if (lane < 32) p += q1 * rec2(QKh, QKl, kb + 64 + lane);
#pragma unroll
                for (int m = 32; m >= 1; m >>= 1) p += __shfl_xor(p, m);
                if (lane == 0)
                    wv[wave][jj] = __expf(p * (1.0f / 256.0f) * QKSCALE) * invl;
            }
        }
        __syncthreads();
        for (int jj = 0; jj < ch; jj++)
            acc += wv[h][jj] * vbuf[(size_t)pidx[jj] * DIMM + tid];
    }
    split2(acc * 16.0f, &oh[(size_t)i * DIMM + tid], &ol[(size_t)i * DIMM + tid]);
}

extern "C" void kernel_launch(void* const* d_in, const int* in_sizes, int n_in,
                              void* d_out, int out_size, void* d_ws, size_t ws_size,
                              hipStream_t stream) {
    const float* x = (const float*)d_in[0];
    const int* labels = (const int*)d_in[1];
    const float* Wqkv = (const float*)d_in[2];
    const float* Wout = (const float*)d_in[3];
    float* out = (float*)d_out;

    char* ws = (char*)d_ws;
    size_t off = 0;
    auto alloc = [&](size_t bytes) -> void* {
        void* p = ws + off;
        off += (bytes + 255) & ~(size_t)255;
        return p;
    };
    _Float16* Xh   = (_Float16*)alloc((size_t)BB * DIMM * 2);
    _Float16* Xl   = (_Float16*)alloc((size_t)BB * DIMM * 2);
    _Float16* WqTh = (_Float16*)alloc((size_t)2304 * DIMM * 2);
    _Float16* WqTl = (_Float16*)alloc((size_t)2304 * DIMM * 2);
    _Float16* WoTh = (_Float16*)alloc((size_t)DIMM * DIMM * 2);
    _Float16* WoTl = (_Float16*)alloc((size_t)DIMM * DIMM * 2);
    _Float16* QKh  = (_Float16*)alloc((size_t)BB * 1536 * 2);
    _Float16* QKl  = (_Float16*)alloc((size_t)BB * 1536 * 2);
    float* vbuf    = (float*)alloc((size_t)BB * DIMM * 4);
    float* lsum    = (float*)alloc((size_t)NHEADS * BB * 4);
    _Float16* Oh   = (_Float16*)alloc((size_t)BB * DIMM * 2);
    _Float16* Ol   = (_Float16*)alloc((size_t)BB * DIMM * 2);
    int* perm      = (int*)alloc(BB * 4);
    int* gstart    = (int*)alloc(1024 * 4);
    int* gcnt      = (int*)alloc(1024 * 4);

    k_zero<<<dim3((NHEADS * BB + 255) / 256), dim3(256), 0, stream>>>(lsum, NHEADS * BB);
    k_split<<<dim3((BB * DIMM + 255) / 256), dim3(256), 0, stream>>>(x, Xh, Xl, 16.0f, BB * DIMM);
    k_tsplit<<<dim3(2304 / 32, DIMM / 32), dim3(32, 8), 0, stream>>>(Wqkv, WqTh, WqTl, 256.0f, DIMM, 2304);
    k_tsplit<<<dim3(DIMM / 32, DIMM / 32), dim3(32, 8), 0, stream>>>(Wout, WoTh, WoTl, 256.0f, DIMM, DIMM);
    k_groups<<<dim3(1), dim3(1024), 0, stream>>>(labels, perm, gstart, gcnt);

    // qkv = x @ Wqkv : A scale 16, B scale 256 -> inv 1/4096
    k_gemm<0><<<dim3(2304 / 128, BB / 128, 1), dim3(256), 0, stream>>>(
        Xh, Xl, DIMM, WqTh, WqTl, DIMM, DIMM, 1.0f / 4096.0f, vbuf, QKh, QKl);
    // row sums of exp(q.k * scale), hi-only
    k_qksum<<<dim3(32, 32), dim3(256), 0, stream>>>(QKh, lsum);
    // masked PV
    k_pv<<<dim3(BB), dim3(768), 0, stream>>>(QKh, QKl, vbuf, lsum, labels, perm, gstart, gcnt, Oh, Ol);
    // out = O @ Wout : inv 1/4096
    k_gemm<1><<<dim3(DIMM / 128, BB / 128, 1), dim3(256), 0, stream>>>(
        Oh, Ol, DIMM, WoTh, WoTl, DIMM, DIMM, 1.0f / 4096.0f, out, nullptr, nullptr);
}